// Round 13
// baseline (254.856 us; speedup 1.0000x reference)
//
#include <hip/hip_runtime.h>
#include <hip/hip_fp16.h>
#include <math.h>

#define NNODE 20000
#define NEDGE 1280000
#define HSTEP (1.0f/24.0f)
#define NBUCK 313          // sort buckets of 64 nodes: node >> 6
#define CAP   4608         // per-bucket slot capacity
#define EPB   1024         // edges per partition block
#define NPB   40           // nodes per persistent block
#define TPB   320          // threads per persistent block (5 waves, 8 lanes/node)
#define NBLK  (NNODE/NPB)  // 500 persistent blocks -> <=2 per CU
#define CAPB  2976         // per-block LDS edge capacity (mean 2560, +8 sigma)
#define NGRP  25           // release-broadcast groups
#define GSZ   20           // blocks per group (NGRP*GSZ == NBLK)
#define XSTR  160256       // carousel buffer stride (bytes, 64B-aligned, half4 x)

// barrier word indices (each on its own 128B line)
#define GEPI(g)   (32*(g))          // per-group epoch, g<25
#define RCNTI(g)  (32*(25+(g)))     // registration group counters
#define XARRI(x)  (32*(50+(x)))     // per-XCD phase arrival counters
#define XCNTI(x)  (32*(58+(x)))     // per-XCD block counts (registration)
#define MASTERI   (32*66)
#define RMASTERI  (32*67)

#define AGT __HIP_MEMORY_SCOPE_AGENT

// ---- init: x0 (half4), sort cursors, barrier words ------------------------
__global__ void rd_init(const float* __restrict__ inp,
                        uint2* __restrict__ xh,
                        int* __restrict__ cursor,
                        int* __restrict__ bar) {
    int n = blockIdx.x * blockDim.x + threadIdx.x;
    if (n < NBUCK) cursor[n] = n * CAP;
    if (n < 2560) bar[n] = 0;
    if (n < NNODE) {
        float x0 = inp[0 * NNODE * 12 + n * 12 + 11];
        float x1 = inp[1 * NNODE * 12 + n * 12 + 11];
        float x2 = inp[2 * NNODE * 12 + n * 12 + 11];
        float x3 = inp[3 * NNODE * 12 + n * 12 + 11];
        __half2 lo = __floats2half2_rn(x0, x1);
        __half2 hi = __floats2half2_rn(x2, x3);
        uint2 st;
        st.x = *(unsigned*)&lo;
        st.y = *(unsigned*)&hi;
        xh[n] = st;
    }
}

// ---- partition into fixed-slot buckets; vectorized, rank cached in LDS ----
__global__ __launch_bounds__(256) void rd_part(const int4* __restrict__ src4,
                                               const int4* __restrict__ dst4,
                                               const float4* __restrict__ w4,
                                               int* __restrict__ cursor,
                                               uint2* __restrict__ rec) {
    __shared__ int h[4][NBUCK];
    __shared__ uint4 cache[EPB / 4];
    int t = threadIdx.x, wv = t >> 6;
    for (int i = t; i < 4 * NBUCK; i += 256) ((int*)h)[i] = 0;
    __syncthreads();
    int q0 = blockIdx.x * (EPB / 4);
    {
        int qi = q0 + t;
        int4 d4 = dst4[qi];
        int dd[4] = {d4.x, d4.y, d4.z, d4.w};
        unsigned cc[4];
        #pragma unroll
        for (int u = 0; u < 4; ++u) {
            int rank = atomicAdd(&h[wv][dd[u] >> 6], 1);
            cc[u] = (unsigned)dd[u] | ((unsigned)rank << 15);
        }
        cache[t] = make_uint4(cc[0], cc[1], cc[2], cc[3]);
    }
    __syncthreads();
    for (int i = t; i < NBUCK; i += 256) {
        int c0 = h[0][i], c1 = h[1][i], c2 = h[2][i], c3 = h[3][i];
        int tot = c0 + c1 + c2 + c3;
        int gb = tot ? atomicAdd(&cursor[i], tot) : 0;
        h[0][i] = gb;
        h[1][i] = gb + c0;
        h[2][i] = gb + c0 + c1;
        h[3][i] = gb + c0 + c1 + c2;
    }
    __syncthreads();
    {
        int qi = q0 + t;
        int4 s4 = src4[qi];
        float4 wa = w4[qi];
        float4 wb = w4[NEDGE / 4 + qi];
        uint4 c4 = cache[t];
        int ss[4] = {s4.x, s4.y, s4.z, s4.w};
        float fa[4] = {wa.x, wa.y, wa.z, wa.w};
        float fb[4] = {wb.x, wb.y, wb.z, wb.w};
        unsigned cc[4] = {c4.x, c4.y, c4.z, c4.w};
        #pragma unroll
        for (int u = 0; u < 4; ++u) {
            int d = cc[u] & 0x7FFF;
            int rank = (int)(cc[u] >> 15);
            int b = d >> 6;
            int p = h[wv][b] + rank;
            float s0 = 1.0f / (1.0f + expf(-fa[u]));
            float s1 = 1.0f / (1.0f + expf(-fb[u]));
            __half2 hh = __floats2half2_rn(s0, s1);
            uint2 rq;
            rq.x = (unsigned)ss[u] | ((unsigned)(d & 63) << 16);
            rq.y = *(unsigned*)&hh;
            if (p < (b + 1) * CAP) rec[p] = rq;   // statistically never false
        }
    }
}

// ---- scan 313 bucket counts -> compact bases ------------------------------
__global__ void rd_bscan(const int* __restrict__ cursor, int* __restrict__ boff) {
    int lane = threadIdx.x;          // single block of 64
    int carry = 0;
    #pragma unroll
    for (int c = 0; c < 5; ++c) {
        int i = c * 64 + lane;
        int v = (i < NBUCK) ? (cursor[i] - i * CAP) : 0;
        int incl = v;
        #pragma unroll
        for (int o = 1; o < 64; o <<= 1) {
            int u = __shfl_up(incl, o, 64);
            if (lane >= o) incl += u;
        }
        if (i < NBUCK) boff[i] = carry + incl - v;
        carry += __shfl(incl, 63, 64);
    }
    if (lane == 0) boff[NBUCK] = carry;   // == NEDGE
}

// ---- per-bucket LDS counting sort -> split arrays + node offsets ----------
__global__ __launch_bounds__(1024) void rd_bsort(const uint2* __restrict__ rec,
                                                 const int* __restrict__ cursor,
                                                 const int* __restrict__ boff,
                                                 unsigned short* __restrict__ es16,
                                                 unsigned* __restrict__ ew32,
                                                 int* __restrict__ offsets) {
    __shared__ uint2 rs[CAP];
    __shared__ int h[64], excl[64];
    int b = blockIdx.x;
    int ib = b * CAP;
    int cnt = cursor[b] - ib; if (cnt > CAP) cnt = CAP;
    int ob = boff[b];
    if (threadIdx.x < 64) h[threadIdx.x] = 0;
    __syncthreads();
    for (int i = threadIdx.x; i < cnt; i += 1024) {
        uint2 q = rec[ib + i];
        rs[i] = q;
        atomicAdd(&h[(q.x >> 16) & 63], 1);
    }
    __syncthreads();
    if (threadIdx.x < 64) {
        int lane = threadIdx.x;
        int v = h[lane];
        int incl = v;
        #pragma unroll
        for (int o = 1; o < 64; o <<= 1) {
            int u = __shfl_up(incl, o, 64);
            if (lane >= o) incl += u;
        }
        excl[lane] = incl - v;
        int n = b * 64 + lane;
        if (n < NNODE) offsets[n] = ob + excl[lane];
        h[lane] = 0;
    }
    if (b == NBUCK - 1 && threadIdx.x == 0) offsets[NNODE] = NEDGE;
    __syncthreads();
    for (int i = threadIdx.x; i < cnt; i += 1024) {
        uint2 q = rs[i];
        int dl = (q.x >> 16) & 63;
        int rank = atomicAdd(&h[dl], 1);
        int p = ob + excl[dl] + rank;
        es16[p] = (unsigned short)(q.x & 0xFFFFu);
        ew32[p] = q.y;
    }
}

// ---- persistent kernel: 24 sub-steps; half4 x-exchange; reg-carried own x -
__global__ __launch_bounds__(TPB, 3) void rd_run(
        const float* __restrict__ inp, const uint2* __restrict__ x0h,
        char* __restrict__ recb,
        const unsigned short* __restrict__ es16,
        const unsigned* __restrict__ ew32,
        const int* __restrict__ offsets,
        const float* __restrict__ r, const float* __restrict__ gate,
        float* __restrict__ out, int* bar) {
    __shared__ uint2 lrec[CAPB];       // {src, half2(s0,s1)} interleaved
    __shared__ int lofs[NPB + 1];
    __shared__ float lgate[24];
    int t = threadIdx.x;
    int n0 = blockIdx.x * NPB;
    if (t <= NPB) lofs[t] = offsets[n0 + t];
    if (t >= 64 && t < 88) lgate[t - 64] = gate[t - 64];
    __syncthreads();
    int ebase = lofs[0];
    int ecnt  = lofs[NPB] - ebase; if (ecnt > CAPB) ecnt = CAPB;
    for (int i = t; i < ecnt; i += TPB)
        lrec[i] = make_uint2((unsigned)es16[ebase + i], ew32[ebase + i]);
    int node = n0 + (t >> 3);
    int sub  = t & 7;
    float r0n = r[node], r1n = r[NNODE + node];
    // own-node x carried in registers (full f32, all 24 phases)
    float4 xreg;
    xreg.x = inp[0 * NNODE * 12 + node * 12 + 11];
    xreg.y = inp[1 * NNODE * 12 + node * 12 + 11];
    xreg.z = inp[2 * NNODE * 12 + node * 12 + 11];
    xreg.w = inp[3 * NNODE * 12 + node * 12 + 11];
    int jb = lofs[t >> 3] - ebase;
    int je = lofs[(t >> 3) + 1] - ebase;
    int grp = blockIdx.x / GSZ;

    // one-time: clear stale (prev-replay) cache lines; register this XCD
    int myxcd = 0, nx = 0, nxcd = 0;
    if (t == 0) {
        __builtin_amdgcn_fence(__ATOMIC_ACQUIRE, "agent");   // inv L1+L2 once
        myxcd = (int)(__builtin_amdgcn_s_getreg(63508) & 0xF);   // HW_REG_XCC_ID
        __hip_atomic_fetch_add(&bar[XCNTI(myxcd)], 1, __ATOMIC_RELAXED, AGT);
        int rA = __hip_atomic_fetch_add(&bar[RCNTI(grp)], 1, __ATOMIC_RELEASE, AGT);
        if (rA == GSZ - 1) {
            int rm = __hip_atomic_fetch_add(&bar[RMASTERI], 1, __ATOMIC_RELAXED, AGT);
            if (rm == NGRP - 1)
                for (int g = 0; g < NGRP; ++g)
                    __hip_atomic_store(&bar[GEPI(g)], 1, __ATOMIC_RELAXED, AGT);
        }
        while (__hip_atomic_load(&bar[GEPI(grp)], __ATOMIC_RELAXED, AGT) < 1)
            __builtin_amdgcn_s_sleep(1);
        asm volatile("" ::: "memory");
        nx = __hip_atomic_load(&bar[XCNTI(myxcd)], __ATOMIC_RELAXED, AGT);
        for (int x2 = 0; x2 < 8; ++x2)
            nxcd += (__hip_atomic_load(&bar[XCNTI(x2)], __ATOMIC_RELAXED, AGT) > 0);
    }
    __syncthreads();

    // one-time per-node sigmoid sums: wsum(phase) = g0*S0 + g1*S1
    float S0 = 0.f, S1 = 0.f;
    for (int j = jb + sub; j < je; j += 8) {
        uint2 q = lrec[j];
        float2 f = __half22float2(*(__half2*)&q.y);
        S0 += f.x; S1 += f.y;
    }
    #pragma unroll
    for (int m = 4; m >= 1; m >>= 1) {
        S0 += __shfl_xor(S0, m, 64);
        S1 += __shfl_xor(S1, m, 64);
    }

    for (int p = 0; p < 24; ++p) {
        int itv = p >> 1;
        float ga = lgate[2 * itv], gb = lgate[2 * itv + 1];
        float g0 = 1.0f / (1.0f + expf(gb - ga));
        float g1 = 1.0f - g0;
        float rc = fmaf(g0, r0n, g1 * r1n);
        float wsum = fmaf(g0, S0, g1 * S1);
        const uint2* xi = p ? (const uint2*)(recb + (size_t)(p - 1) * XSTR) : x0h;
        uint2*       xo = (uint2*)(recb + (size_t)p * XSTR);

        float4 acc = make_float4(0.f, 0.f, 0.f, 0.f);
        int j = jb + sub;
        // 8-wide: typical node (deg~64) does exactly one iteration
        for (; j + 56 < je; j += 64) {
            uint2 q0 = lrec[j],      q1 = lrec[j +  8], q2 = lrec[j + 16], q3 = lrec[j + 24];
            uint2 q4 = lrec[j + 32], q5 = lrec[j + 40], q6 = lrec[j + 48], q7 = lrec[j + 56];
            uint2 g0v = xi[q0.x], g1v = xi[q1.x], g2v = xi[q2.x], g3v = xi[q3.x];
            uint2 g4v = xi[q4.x], g5v = xi[q5.x], g6v = xi[q6.x], g7v = xi[q7.x];
            #define WE(qq) ({ float2 f_ = __half22float2(*(__half2*)&qq.y); fmaf(g0, f_.x, g1 * f_.y); })
            #define ACC4(gv, we) { \
                float2 lo_ = __half22float2(*(__half2*)&gv.x); \
                float2 hi_ = __half22float2(*(__half2*)&gv.y); \
                acc.x = fmaf(we, lo_.x, acc.x); \
                acc.y = fmaf(we, lo_.y, acc.y); \
                acc.z = fmaf(we, hi_.x, acc.z); \
                acc.w = fmaf(we, hi_.y, acc.w); }
            float we0 = WE(q0), we1 = WE(q1), we2 = WE(q2), we3 = WE(q3);
            float we4 = WE(q4), we5 = WE(q5), we6 = WE(q6), we7 = WE(q7);
            ACC4(g0v, we0) ACC4(g1v, we1) ACC4(g2v, we2) ACC4(g3v, we3)
            ACC4(g4v, we4) ACC4(g5v, we5) ACC4(g6v, we6) ACC4(g7v, we7)
        }
        // 4-wide remainder
        if (j + 24 < je) {
            uint2 q0 = lrec[j], q1 = lrec[j + 8], q2 = lrec[j + 16], q3 = lrec[j + 24];
            uint2 g0v = xi[q0.x], g1v = xi[q1.x], g2v = xi[q2.x], g3v = xi[q3.x];
            float we0 = WE(q0), we1 = WE(q1), we2 = WE(q2), we3 = WE(q3);
            ACC4(g0v, we0) ACC4(g1v, we1) ACC4(g2v, we2) ACC4(g3v, we3)
            j += 32;
        }
        // 2-wide remainder
        if (j + 8 < je) {
            uint2 q0 = lrec[j], q1 = lrec[j + 8];
            uint2 g0v = xi[q0.x], g1v = xi[q1.x];
            float we0 = WE(q0), we1 = WE(q1);
            ACC4(g0v, we0) ACC4(g1v, we1)
            j += 16;
        }
        // 1-wide remainder
        if (j < je) {
            uint2 q0 = lrec[j];
            uint2 g0v = xi[q0.x];
            float we0 = WE(q0);
            ACC4(g0v, we0)
        }
        #pragma unroll
        for (int m = 4; m >= 1; m >>= 1) {
            acc.x += __shfl_xor(acc.x, m, 64);
            acc.y += __shfl_xor(acc.y, m, 64);
            acc.z += __shfl_xor(acc.z, m, 64);
            acc.w += __shfl_xor(acc.w, m, 64);
        }
        float4 xd = xreg;
        float4 xn;
        xn.x = xd.x + HSTEP * ((acc.x - wsum * xd.x) + rc * xd.x * (1.0f - xd.x));
        xn.y = xd.y + HSTEP * ((acc.y - wsum * xd.y) + rc * xd.y * (1.0f - xd.y));
        xn.z = xd.z + HSTEP * ((acc.z - wsum * xd.z) + rc * xd.z * (1.0f - xd.z));
        xn.w = xd.w + HSTEP * ((acc.w - wsum * xd.w) + rc * xd.w * (1.0f - xd.w));
        xreg = xn;
        if (sub == 0) {
            __half2 lo = __floats2half2_rn(xn.x, xn.y);
            __half2 hi = __floats2half2_rn(xn.z, xn.w);
            uint2 st;
            st.x = *(unsigned*)&lo;
            st.y = *(unsigned*)&hi;
            xo[node] = st;
        }
        if ((p & 1) && sub < 4) {
            float v = (sub == 0) ? xn.x : (sub == 1) ? xn.y : (sub == 2) ? xn.z : xn.w;
            out[(itv * 4 + sub) * NNODE + node] = v;
        }

        if (p < 23) {
            __syncthreads();               // compiler drains vmcnt(0) per wave
            if (t == 0) {
                int o = __hip_atomic_fetch_add(&bar[XARRI(myxcd)], 1,
                                               __ATOMIC_RELAXED, AGT);
                if (o == (p + 1) * nx - 1) {       // last block on this XCD
                    __builtin_amdgcn_fence(__ATOMIC_RELEASE, "agent");  // 1 wbl2/XCD
                    int om = __hip_atomic_fetch_add(&bar[MASTERI], 1,
                                                    __ATOMIC_RELAXED, AGT);
                    if (om == (p + 1) * nxcd - 1)  // last XCD -> broadcast
                        for (int g = 0; g < NGRP; ++g)
                            __hip_atomic_store(&bar[GEPI(g)], p + 2,
                                               __ATOMIC_RELAXED, AGT);
                }
                while (__hip_atomic_load(&bar[GEPI(grp)], __ATOMIC_RELAXED, AGT) < p + 2)
                    __builtin_amdgcn_s_sleep(1);
                asm volatile("" ::: "memory");
            }
            __syncthreads();
        }
    }
}

extern "C" void kernel_launch(void* const* d_in, const int* in_sizes, int n_in,
                              void* d_out, int out_size, void* d_ws, size_t ws_size,
                              hipStream_t stream) {
    const float* inp  = (const float*)d_in[0];
    const float* gate = (const float*)d_in[1];
    const float* w    = (const float*)d_in[2];
    const float* r    = (const float*)d_in[3];
    const int*   src  = (const int*)d_in[4];
    const int*   dst  = (const int*)d_in[5];
    float* out = (float*)d_out;

    char* ws = (char*)d_ws;
    uint2*          xH      = (uint2*) (ws + 0);          // 160,000 B (half4 x0)
    int*            offsets = (int*)   (ws + 641024);     // 20001 ints
    int*            cursor  = (int*)   (ws + 721152);     // 313 ints
    int*            boff    = (int*)   (ws + 722432);     // 314 ints
    int*            bar     = (int*)   (ws + 723712);     // 2560 ints + pad (16 KB)
    char*           recb    = (ws + 740096);              // 11.5 MB (sort rec / x carousel)
    unsigned short* es16    = (unsigned short*)(ws + 12278528); // 2.56 MB
    unsigned*       ew32    = (unsigned*)(ws + 14838528); // 5.12 MB

    rd_init <<<(NNODE + 255) / 256, 256, 0, stream>>>(inp, xH, cursor, bar);
    rd_part <<<NEDGE / EPB, 256, 0, stream>>>((const int4*)src, (const int4*)dst,
                                              (const float4*)w, cursor, (uint2*)recb);
    rd_bscan<<<1, 64, 0, stream>>>(cursor, boff);
    rd_bsort<<<NBUCK, 1024, 0, stream>>>((const uint2*)recb, cursor, boff,
                                         es16, ew32, offsets);
    rd_run  <<<NBLK, TPB, 0, stream>>>(inp, xH, recb, es16, ew32, offsets,
                                       r, gate, out, bar);
}

// Round 14
// 232.828 us; speedup vs baseline: 1.0946x; 1.0946x over previous
//
#include <hip/hip_runtime.h>
#include <hip/hip_fp16.h>
#include <math.h>

#define NNODE 20000
#define NEDGE 1280000
#define HSTEP (1.0f/24.0f)
#define NBUCK 313          // sort buckets of 64 nodes: node >> 6
#define CAP   4608         // per-bucket slot capacity
#define EPB   2048         // edges per partition block
#define NPB   40           // nodes per persistent block
#define TPB   320          // threads per persistent block (5 waves, 8 lanes/node)
#define NBLK  (NNODE/NPB)  // 500 persistent blocks -> <=2 per CU
#define CAPB  2976         // per-block LDS edge capacity (mean 2560, +8 sigma)
#define NGRP  25           // release-broadcast groups
#define GSZ   20           // blocks per group (NGRP*GSZ == NBLK)
#define XSTR  160256       // carousel buffer stride (bytes, 64B-aligned, half4 x)

// barrier word indices (each on its own 128B line)
#define GEPI(g)   (32*(g))          // per-group epoch, g<25
#define RCNTI(g)  (32*(25+(g)))     // registration group counters
#define XARRI(x)  (32*(50+(x)))     // per-XCD phase arrival counters
#define XCNTI(x)  (32*(58+(x)))     // per-XCD block counts (registration)
#define MASTERI   (32*66)
#define RMASTERI  (32*67)

#define AGT __HIP_MEMORY_SCOPE_AGENT

// ---- init: x0 (half4), sort cursors, barrier words ------------------------
__global__ void rd_init(const float* __restrict__ inp,
                        uint2* __restrict__ xh,
                        int* __restrict__ cursor,
                        int* __restrict__ bar) {
    int n = blockIdx.x * blockDim.x + threadIdx.x;
    if (n < NBUCK) cursor[n] = n * CAP;
    if (n < 2560) bar[n] = 0;
    if (n < NNODE) {
        float x0 = inp[0 * NNODE * 12 + n * 12 + 11];
        float x1 = inp[1 * NNODE * 12 + n * 12 + 11];
        float x2 = inp[2 * NNODE * 12 + n * 12 + 11];
        float x3 = inp[3 * NNODE * 12 + n * 12 + 11];
        __half2 lo = __floats2half2_rn(x0, x1);
        __half2 hi = __floats2half2_rn(x2, x3);
        uint2 st;
        st.x = *(unsigned*)&lo;
        st.y = *(unsigned*)&hi;
        xh[n] = st;
    }
}

// ---- partition into fixed-slot buckets; vectorized, rank cached in LDS ----
__global__ __launch_bounds__(256) void rd_part(const int4* __restrict__ src4,
                                               const int4* __restrict__ dst4,
                                               const float4* __restrict__ w4,
                                               int* __restrict__ cursor,
                                               uint2* __restrict__ rec) {
    __shared__ int h[4][NBUCK];
    __shared__ uint4 cache[EPB / 4];
    int t = threadIdx.x, wv = t >> 6;
    for (int i = t; i < 4 * NBUCK; i += 256) ((int*)h)[i] = 0;
    __syncthreads();
    int q0 = blockIdx.x * (EPB / 4);
    #pragma unroll
    for (int k = 0; k < 2; ++k) {
        int qi = q0 + k * 256 + t;
        int4 d4 = dst4[qi];
        int dd[4] = {d4.x, d4.y, d4.z, d4.w};
        unsigned cc[4];
        #pragma unroll
        for (int u = 0; u < 4; ++u) {
            int rank = atomicAdd(&h[wv][dd[u] >> 6], 1);
            cc[u] = (unsigned)dd[u] | ((unsigned)rank << 15);
        }
        cache[k * 256 + t] = make_uint4(cc[0], cc[1], cc[2], cc[3]);
    }
    __syncthreads();
    for (int i = t; i < NBUCK; i += 256) {
        int c0 = h[0][i], c1 = h[1][i], c2 = h[2][i], c3 = h[3][i];
        int tot = c0 + c1 + c2 + c3;
        int gb = tot ? atomicAdd(&cursor[i], tot) : 0;
        h[0][i] = gb;
        h[1][i] = gb + c0;
        h[2][i] = gb + c0 + c1;
        h[3][i] = gb + c0 + c1 + c2;
    }
    __syncthreads();
    #pragma unroll
    for (int k = 0; k < 2; ++k) {
        int qi = q0 + k * 256 + t;
        int4 s4 = src4[qi];
        float4 wa = w4[qi];
        float4 wb = w4[NEDGE / 4 + qi];
        uint4 c4 = cache[k * 256 + t];
        int ss[4] = {s4.x, s4.y, s4.z, s4.w};
        float fa[4] = {wa.x, wa.y, wa.z, wa.w};
        float fb[4] = {wb.x, wb.y, wb.z, wb.w};
        unsigned cc[4] = {c4.x, c4.y, c4.z, c4.w};
        #pragma unroll
        for (int u = 0; u < 4; ++u) {
            int d = cc[u] & 0x7FFF;
            int rank = (int)(cc[u] >> 15);
            int b = d >> 6;
            int p = h[wv][b] + rank;
            float s0 = 1.0f / (1.0f + expf(-fa[u]));
            float s1 = 1.0f / (1.0f + expf(-fb[u]));
            __half2 hh = __floats2half2_rn(s0, s1);
            uint2 rq;
            rq.x = (unsigned)ss[u] | ((unsigned)(d & 63) << 16);
            rq.y = *(unsigned*)&hh;
            if (p < (b + 1) * CAP) rec[p] = rq;   // statistically never false
        }
    }
}

// ---- scan 313 bucket counts -> compact bases ------------------------------
__global__ void rd_bscan(const int* __restrict__ cursor, int* __restrict__ boff) {
    int lane = threadIdx.x;          // single block of 64
    int carry = 0;
    #pragma unroll
    for (int c = 0; c < 5; ++c) {
        int i = c * 64 + lane;
        int v = (i < NBUCK) ? (cursor[i] - i * CAP) : 0;
        int incl = v;
        #pragma unroll
        for (int o = 1; o < 64; o <<= 1) {
            int u = __shfl_up(incl, o, 64);
            if (lane >= o) incl += u;
        }
        if (i < NBUCK) boff[i] = carry + incl - v;
        carry += __shfl(incl, 63, 64);
    }
    if (lane == 0) boff[NBUCK] = carry;   // == NEDGE
}

// ---- per-bucket LDS counting sort -> split arrays + node offsets ----------
__global__ __launch_bounds__(512) void rd_bsort(const uint2* __restrict__ rec,
                                                const int* __restrict__ cursor,
                                                const int* __restrict__ boff,
                                                unsigned short* __restrict__ es16,
                                                unsigned* __restrict__ ew32,
                                                int* __restrict__ offsets) {
    __shared__ uint2 rs[CAP];
    __shared__ int h[64], excl[64];
    int b = blockIdx.x;
    int ib = b * CAP;
    int cnt = cursor[b] - ib; if (cnt > CAP) cnt = CAP;
    int ob = boff[b];
    if (threadIdx.x < 64) h[threadIdx.x] = 0;
    __syncthreads();
    for (int i = threadIdx.x; i < cnt; i += 512) {
        uint2 q = rec[ib + i];
        rs[i] = q;
        atomicAdd(&h[(q.x >> 16) & 63], 1);
    }
    __syncthreads();
    if (threadIdx.x < 64) {
        int lane = threadIdx.x;
        int v = h[lane];
        int incl = v;
        #pragma unroll
        for (int o = 1; o < 64; o <<= 1) {
            int u = __shfl_up(incl, o, 64);
            if (lane >= o) incl += u;
        }
        excl[lane] = incl - v;
        int n = b * 64 + lane;
        if (n < NNODE) offsets[n] = ob + excl[lane];
        h[lane] = 0;
    }
    if (b == NBUCK - 1 && threadIdx.x == 0) offsets[NNODE] = NEDGE;
    __syncthreads();
    for (int i = threadIdx.x; i < cnt; i += 512) {
        uint2 q = rs[i];
        int dl = (q.x >> 16) & 63;
        int rank = atomicAdd(&h[dl], 1);
        int p = ob + excl[dl] + rank;
        es16[p] = (unsigned short)(q.x & 0xFFFFu);
        ew32[p] = q.y;
    }
}

// ---- persistent kernel: 24 sub-steps; half4 x-exchange; reg-carried own x -
__global__ __launch_bounds__(TPB, 3) void rd_run(
        const float* __restrict__ inp, const uint2* __restrict__ x0h,
        char* __restrict__ recb,
        const unsigned short* __restrict__ es16,
        const unsigned* __restrict__ ew32,
        const int* __restrict__ offsets,
        const float* __restrict__ r, const float* __restrict__ gate,
        float* __restrict__ out, int* bar) {
    __shared__ uint2 lrec[CAPB];       // {src, half2(s0,s1)} interleaved
    __shared__ int lofs[NPB + 1];
    __shared__ float lgate[24];
    int t = threadIdx.x;
    int n0 = blockIdx.x * NPB;
    if (t <= NPB) lofs[t] = offsets[n0 + t];
    if (t >= 64 && t < 88) lgate[t - 64] = gate[t - 64];
    __syncthreads();
    int ebase = lofs[0];
    int ecnt  = lofs[NPB] - ebase; if (ecnt > CAPB) ecnt = CAPB;
    for (int i = t; i < ecnt; i += TPB)
        lrec[i] = make_uint2((unsigned)es16[ebase + i], ew32[ebase + i]);
    int node = n0 + (t >> 3);
    int sub  = t & 7;
    float r0n = r[node], r1n = r[NNODE + node];
    // own-node x carried in registers (full f32, all 24 phases)
    float4 xreg;
    xreg.x = inp[0 * NNODE * 12 + node * 12 + 11];
    xreg.y = inp[1 * NNODE * 12 + node * 12 + 11];
    xreg.z = inp[2 * NNODE * 12 + node * 12 + 11];
    xreg.w = inp[3 * NNODE * 12 + node * 12 + 11];
    int jb = lofs[t >> 3] - ebase;
    int je = lofs[(t >> 3) + 1] - ebase;
    int grp = blockIdx.x / GSZ;

    // one-time: clear stale (prev-replay) cache lines; register this XCD
    int myxcd = 0, nx = 0, nxcd = 0;
    if (t == 0) {
        __builtin_amdgcn_fence(__ATOMIC_ACQUIRE, "agent");   // inv L1+L2 once
        myxcd = (int)(__builtin_amdgcn_s_getreg(63508) & 0xF);   // HW_REG_XCC_ID
        __hip_atomic_fetch_add(&bar[XCNTI(myxcd)], 1, __ATOMIC_RELAXED, AGT);
        int rA = __hip_atomic_fetch_add(&bar[RCNTI(grp)], 1, __ATOMIC_RELEASE, AGT);
        if (rA == GSZ - 1) {
            int rm = __hip_atomic_fetch_add(&bar[RMASTERI], 1, __ATOMIC_RELAXED, AGT);
            if (rm == NGRP - 1)
                for (int g = 0; g < NGRP; ++g)
                    __hip_atomic_store(&bar[GEPI(g)], 1, __ATOMIC_RELAXED, AGT);
        }
        while (__hip_atomic_load(&bar[GEPI(grp)], __ATOMIC_RELAXED, AGT) < 1)
            __builtin_amdgcn_s_sleep(2);
        asm volatile("" ::: "memory");
        nx = __hip_atomic_load(&bar[XCNTI(myxcd)], __ATOMIC_RELAXED, AGT);
        for (int x2 = 0; x2 < 8; ++x2)
            nxcd += (__hip_atomic_load(&bar[XCNTI(x2)], __ATOMIC_RELAXED, AGT) > 0);
    }
    __syncthreads();

    // one-time per-node sigmoid sums: wsum(phase) = g0*S0 + g1*S1
    float S0 = 0.f, S1 = 0.f;
    for (int j = jb + sub; j < je; j += 8) {
        uint2 q = lrec[j];
        float2 f = __half22float2(*(__half2*)&q.y);
        S0 += f.x; S1 += f.y;
    }
    #pragma unroll
    for (int m = 4; m >= 1; m >>= 1) {
        S0 += __shfl_xor(S0, m, 64);
        S1 += __shfl_xor(S1, m, 64);
    }

    for (int p = 0; p < 24; ++p) {
        int itv = p >> 1;
        float ga = lgate[2 * itv], gb = lgate[2 * itv + 1];
        float g0 = 1.0f / (1.0f + expf(gb - ga));
        float g1 = 1.0f - g0;
        float rc = fmaf(g0, r0n, g1 * r1n);
        float wsum = fmaf(g0, S0, g1 * S1);
        const uint2* xi = p ? (const uint2*)(recb + (size_t)(p - 1) * XSTR) : x0h;
        uint2*       xo = (uint2*)(recb + (size_t)p * XSTR);

        float4 acc = make_float4(0.f, 0.f, 0.f, 0.f);
        int j = jb + sub;
        // 8-wide: typical node (deg~64) does exactly one iteration
        for (; j + 56 < je; j += 64) {
            uint2 q0 = lrec[j],      q1 = lrec[j +  8], q2 = lrec[j + 16], q3 = lrec[j + 24];
            uint2 q4 = lrec[j + 32], q5 = lrec[j + 40], q6 = lrec[j + 48], q7 = lrec[j + 56];
            uint2 g0v = xi[q0.x], g1v = xi[q1.x], g2v = xi[q2.x], g3v = xi[q3.x];
            uint2 g4v = xi[q4.x], g5v = xi[q5.x], g6v = xi[q6.x], g7v = xi[q7.x];
            #define WE(qq) ({ float2 f_ = __half22float2(*(__half2*)&qq.y); fmaf(g0, f_.x, g1 * f_.y); })
            #define ACC4(gv, we) { \
                float2 lo_ = __half22float2(*(__half2*)&gv.x); \
                float2 hi_ = __half22float2(*(__half2*)&gv.y); \
                acc.x = fmaf(we, lo_.x, acc.x); \
                acc.y = fmaf(we, lo_.y, acc.y); \
                acc.z = fmaf(we, hi_.x, acc.z); \
                acc.w = fmaf(we, hi_.y, acc.w); }
            float we0 = WE(q0), we1 = WE(q1), we2 = WE(q2), we3 = WE(q3);
            float we4 = WE(q4), we5 = WE(q5), we6 = WE(q6), we7 = WE(q7);
            ACC4(g0v, we0) ACC4(g1v, we1) ACC4(g2v, we2) ACC4(g3v, we3)
            ACC4(g4v, we4) ACC4(g5v, we5) ACC4(g6v, we6) ACC4(g7v, we7)
        }
        // 4-wide remainder
        if (j + 24 < je) {
            uint2 q0 = lrec[j], q1 = lrec[j + 8], q2 = lrec[j + 16], q3 = lrec[j + 24];
            uint2 g0v = xi[q0.x], g1v = xi[q1.x], g2v = xi[q2.x], g3v = xi[q3.x];
            float we0 = WE(q0), we1 = WE(q1), we2 = WE(q2), we3 = WE(q3);
            ACC4(g0v, we0) ACC4(g1v, we1) ACC4(g2v, we2) ACC4(g3v, we3)
            j += 32;
        }
        // 2-wide remainder
        if (j + 8 < je) {
            uint2 q0 = lrec[j], q1 = lrec[j + 8];
            uint2 g0v = xi[q0.x], g1v = xi[q1.x];
            float we0 = WE(q0), we1 = WE(q1);
            ACC4(g0v, we0) ACC4(g1v, we1)
            j += 16;
        }
        // 1-wide remainder
        if (j < je) {
            uint2 q0 = lrec[j];
            uint2 g0v = xi[q0.x];
            float we0 = WE(q0);
            ACC4(g0v, we0)
        }
        #pragma unroll
        for (int m = 4; m >= 1; m >>= 1) {
            acc.x += __shfl_xor(acc.x, m, 64);
            acc.y += __shfl_xor(acc.y, m, 64);
            acc.z += __shfl_xor(acc.z, m, 64);
            acc.w += __shfl_xor(acc.w, m, 64);
        }
        float4 xd = xreg;
        float4 xn;
        xn.x = xd.x + HSTEP * ((acc.x - wsum * xd.x) + rc * xd.x * (1.0f - xd.x));
        xn.y = xd.y + HSTEP * ((acc.y - wsum * xd.y) + rc * xd.y * (1.0f - xd.y));
        xn.z = xd.z + HSTEP * ((acc.z - wsum * xd.z) + rc * xd.z * (1.0f - xd.z));
        xn.w = xd.w + HSTEP * ((acc.w - wsum * xd.w) + rc * xd.w * (1.0f - xd.w));
        xreg = xn;
        if (sub == 0) {
            __half2 lo = __floats2half2_rn(xn.x, xn.y);
            __half2 hi = __floats2half2_rn(xn.z, xn.w);
            uint2 st;
            st.x = *(unsigned*)&lo;
            st.y = *(unsigned*)&hi;
            xo[node] = st;
        }
        if ((p & 1) && sub < 4) {
            float v = (sub == 0) ? xn.x : (sub == 1) ? xn.y : (sub == 2) ? xn.z : xn.w;
            out[(itv * 4 + sub) * NNODE + node] = v;
        }

        if (p < 23) {
            __syncthreads();               // compiler drains vmcnt(0) per wave
            if (t == 0) {
                int o = __hip_atomic_fetch_add(&bar[XARRI(myxcd)], 1,
                                               __ATOMIC_RELAXED, AGT);
                if (o == (p + 1) * nx - 1) {       // last block on this XCD
                    __builtin_amdgcn_fence(__ATOMIC_RELEASE, "agent");  // 1 wbl2/XCD
                    int om = __hip_atomic_fetch_add(&bar[MASTERI], 1,
                                                    __ATOMIC_RELAXED, AGT);
                    if (om == (p + 1) * nxcd - 1)  // last XCD -> broadcast
                        for (int g = 0; g < NGRP; ++g)
                            __hip_atomic_store(&bar[GEPI(g)], p + 2,
                                               __ATOMIC_RELAXED, AGT);
                }
                while (__hip_atomic_load(&bar[GEPI(grp)], __ATOMIC_RELAXED, AGT) < p + 2)
                    __builtin_amdgcn_s_sleep(2);
                asm volatile("" ::: "memory");
            }
            __syncthreads();
        }
    }
}

extern "C" void kernel_launch(void* const* d_in, const int* in_sizes, int n_in,
                              void* d_out, int out_size, void* d_ws, size_t ws_size,
                              hipStream_t stream) {
    const float* inp  = (const float*)d_in[0];
    const float* gate = (const float*)d_in[1];
    const float* w    = (const float*)d_in[2];
    const float* r    = (const float*)d_in[3];
    const int*   src  = (const int*)d_in[4];
    const int*   dst  = (const int*)d_in[5];
    float* out = (float*)d_out;

    char* ws = (char*)d_ws;
    uint2*          xH      = (uint2*) (ws + 0);          // 160,000 B (half4 x0)
    int*            offsets = (int*)   (ws + 641024);     // 20001 ints
    int*            cursor  = (int*)   (ws + 721152);     // 313 ints
    int*            boff    = (int*)   (ws + 722432);     // 314 ints
    int*            bar     = (int*)   (ws + 723712);     // 2560 ints + pad (16 KB)
    char*           recb    = (ws + 740096);              // 11.5 MB (sort rec / x carousel)
    unsigned short* es16    = (unsigned short*)(ws + 12278528); // 2.56 MB
    unsigned*       ew32    = (unsigned*)(ws + 14838528); // 5.12 MB

    rd_init <<<(NNODE + 255) / 256, 256, 0, stream>>>(inp, xH, cursor, bar);
    rd_part <<<NEDGE / EPB, 256, 0, stream>>>((const int4*)src, (const int4*)dst,
                                              (const float4*)w, cursor, (uint2*)recb);
    rd_bscan<<<1, 64, 0, stream>>>(cursor, boff);
    rd_bsort<<<NBUCK, 512, 0, stream>>>((const uint2*)recb, cursor, boff,
                                        es16, ew32, offsets);
    rd_run  <<<NBLK, TPB, 0, stream>>>(inp, xH, recb, es16, ew32, offsets,
                                       r, gate, out, bar);
}